// Round 10
// baseline (79.192 us; speedup 1.0000x reference)
//
#include <hip/hip_runtime.h>
#include <hip/hip_bf16.h>

typedef float  f32x4  __attribute__((ext_vector_type(4)));
typedef short  s16x8  __attribute__((ext_vector_type(8)));
typedef short  s16x4  __attribute__((ext_vector_type(4)));
typedef unsigned short u16x8 __attribute__((ext_vector_type(8)));

#define T_  512
#define D_  512
#define BTD 4194304   // 16*512*512
#define SCALE_Q 0.044194173824159216f   // 1/sqrt(512)

static __device__ __forceinline__ unsigned short f2bf(float f) {
  unsigned u = __builtin_bit_cast(unsigned, f);
  u += 0x7fffu + ((u >> 16) & 1u);
  return (unsigned short)(u >> 16);
}

static __device__ __forceinline__ void gload_lds16(const void* g, void* l) {
  __builtin_amdgcn_global_load_lds(
      (__attribute__((address_space(1))) void*)(g),
      (__attribute__((address_space(3))) void*)(l),
      16, 0, 0);
}

// K=16 bf16 MFMA (v6-proven). asm MFMA: compiler does not insert hazard nops;
// fence (MFMA_FENCE) before any VALU read of the accumulator, s_nop before use.
static __device__ __forceinline__ f32x4 mfma16x16x16(s16x4 a, s16x4 b, f32x4 c) {
  asm("v_mfma_f32_16x16x16_bf16 %0, %1, %2, %0" : "+v"(c) : "v"(a), "v"(b));
  return c;
}
#define MFMA_FENCE()                                   \
  do {                                                 \
    __builtin_amdgcn_sched_barrier(0);                 \
    asm volatile("s_nop 7\n\ts_nop 7");                \
    __builtin_amdgcn_sched_barrier(0);                 \
  } while (0)

// s_barrier without vmcnt drain (prefetches stay in flight); lgkm only.
#define BAR_LGKM()                                          \
  do {                                                      \
    __builtin_amdgcn_sched_barrier(0);                      \
    asm volatile("s_waitcnt lgkmcnt(0)" ::: "memory");      \
    __builtin_amdgcn_sched_barrier(0);                      \
    __builtin_amdgcn_s_barrier();                           \
    __builtin_amdgcn_sched_barrier(0);                      \
  } while (0)

// ---------------------------------------------------------------------------
// 128x128-tile bt-GEMM mainloop, 2-phase pipelined (T3 minimum):
// double-buffered LDS; stage(t+1) issued BEFORE compute(t); ONE barrier/step.
// C += A[M,K] * B[N,K]^T, bf16 MFMA. ldsA/ldsB each 2 x 4096 shorts.
// ---------------------------------------------------------------------------
__device__ __forceinline__ void gemm_mainloop(
    const unsigned short* __restrict__ A,
    const unsigned short* __restrict__ B,
    int lda, int ldb, int ksteps,
    unsigned short* ldsA, unsigned short* ldsB,
    f32x4 acc[4][4])
{
  const int tid  = threadIdx.x;
  const int lane = tid & 63;
  const int wave = tid >> 6;
  const int wr = wave >> 1, wc = wave & 1;

  const int c0 = wave, c1 = wave + 4;
  const int ks0 = c0 >> 1, r00 = (c0 & 1) * 64;
  const int ks1 = c1 >> 1, r01 = (c1 & 1) * 64;

  const int offA = (lane >> 4) * 2048 + (wr * 64 + (lane & 15)) * 16;
  const int offB = (lane >> 4) * 2048 + (wc * 64 + (lane & 15)) * 16;

  auto stage = [&](int kt, int buf) {
    const unsigned short* Ak = A + kt * 32;
    const unsigned short* Bk = B + kt * 32;
    unsigned short* dA = ldsA + buf * 4096;
    unsigned short* dB = ldsB + buf * 4096;
    gload_lds16(Ak + (size_t)(r00 + lane) * lda + ks0 * 8, dA + c0 * 512);
    gload_lds16(Ak + (size_t)(r01 + lane) * lda + ks1 * 8, dA + c1 * 512);
    gload_lds16(Bk + (size_t)(r00 + lane) * ldb + ks0 * 8, dB + c0 * 512);
    gload_lds16(Bk + (size_t)(r01 + lane) * ldb + ks1 * 8, dB + c1 * 512);
  };

  stage(0, 0);
  __syncthreads();                     // prologue drain
  int cur = 0;
  for (int kt = 0; kt < ksteps; ++kt) {
    if (kt + 1 < ksteps) stage(kt + 1, cur ^ 1);   // full compute-phase cover
    const char* ldsAc = (const char*)(ldsA + cur * 4096);
    const char* ldsBc = (const char*)(ldsB + cur * 4096);
    s16x8 af[4], bfr[4];
#pragma unroll
    for (int mi = 0; mi < 4; ++mi)
      af[mi] = *(const s16x8*)(ldsAc + offA + mi * 256);
#pragma unroll
    for (int ni = 0; ni < 4; ++ni)
      bfr[ni] = *(const s16x8*)(ldsBc + offB + ni * 256);
#pragma unroll
    for (int mi = 0; mi < 4; ++mi)
#pragma unroll
      for (int ni = 0; ni < 4; ++ni)
        acc[mi][ni] = __builtin_amdgcn_mfma_f32_16x16x32_bf16(
            af[mi], bfr[ni], acc[mi][ni], 0, 0, 0);
    __syncthreads();                   // drains stage(kt+1) + this step's lgkm
    cur ^= 1;
  }
}

#define ZERO_ACC(acc)                                        \
  _Pragma("unroll") for (int za = 0; za < 4; ++za)           \
  _Pragma("unroll") for (int zb = 0; zb < 4; ++zb)           \
      acc[za][zb] = (f32x4){0.f, 0.f, 0.f, 0.f};

// ---------------------------------------------------------------------------
// prep: rope tables + x->bf16 + W->bf16 (one launch)
// ---------------------------------------------------------------------------
__global__ __launch_bounds__(256) void prep(
    const float* __restrict__ x, const float* __restrict__ W,
    unsigned short* __restrict__ xb, unsigned short* __restrict__ Wb,
    float* __restrict__ cosT, float* __restrict__ sinT)
{
  const int bid = blockIdx.x, tid = threadIdx.x;
  if (bid < 2048) {
    int idx = (bid * 256 + tid) * 8;
    f32x4 a = *(const f32x4*)(x + idx);
    f32x4 b = *(const f32x4*)(x + idx + 4);
    u16x8 o;
    o[0]=f2bf(a[0]); o[1]=f2bf(a[1]); o[2]=f2bf(a[2]); o[3]=f2bf(a[3]);
    o[4]=f2bf(b[0]); o[5]=f2bf(b[1]); o[6]=f2bf(b[2]); o[7]=f2bf(b[3]);
    *(u16x8*)(xb + idx) = o;
  } else if (bid < 2304) {
    int idx = ((bid - 2048) * 256 + tid) * 8;
    f32x4 a = *(const f32x4*)(W + idx);
    f32x4 b = *(const f32x4*)(W + idx + 4);
    u16x8 o;
    o[0]=f2bf(a[0]); o[1]=f2bf(a[1]); o[2]=f2bf(a[2]); o[3]=f2bf(a[3]);
    o[4]=f2bf(b[0]); o[5]=f2bf(b[1]); o[6]=f2bf(b[2]); o[7]=f2bf(b[3]);
    *(u16x8*)(Wb + idx) = o;
  } else {
    int idx = (bid - 2304) * 256 + tid;     // 512*256 entries
    int t = idx >> 8, i = idx & 255;
    float theta = expf(-9.210340371976184f * (float)(2 * i) * (1.0f / 512.0f));
    float s, c;
    sincosf((float)(t + 1) * theta, &s, &c);
    cosT[idx] = c;
    sinT[idx] = s;
  }
}

// ---------------------------------------------------------------------------
// GEMM1: qkv projection (q,k only). q pre-scaled by 1/sqrt(D). k gets RoPE.
// ---------------------------------------------------------------------------
__global__ __launch_bounds__(256) void gemm_qk(
    const unsigned short* __restrict__ xb, const unsigned short* __restrict__ Wb,
    const float* __restrict__ bias, const float* __restrict__ cosT,
    const float* __restrict__ sinT, unsigned short* __restrict__ qb,
    unsigned short* __restrict__ kb) {
  __shared__ __align__(16) unsigned short ldsA[8192];   // 2 buffers
  __shared__ __align__(16) unsigned short ldsB[8192];
  const int bm = blockIdx.x, bn = blockIdx.y;
  f32x4 acc[4][4];
  ZERO_ACC(acc);
  gemm_mainloop(xb + (size_t)bm * 128 * 512, Wb + (size_t)bn * 128 * 512,
                512, 512, 16, ldsA, ldsB, acc);
  const int lane = threadIdx.x & 63, wave = threadIdx.x >> 6;
  const int wr = wave >> 1, wc = wave & 1;
  const int rowbase = bm * 128 + wr * 64 + ((lane >> 4) << 2);
  const int colbase = bn * 128 + wc * 64 + (lane & 15);
  const bool isK = (bn >= 4);
#pragma unroll
  for (int ni = 0; ni < 4; ++ni) {
    const int col = colbase + ni * 16;
    const float bv = bias[col];
#pragma unroll
    for (int mi = 0; mi < 4; ++mi) {
#pragma unroll
      for (int r = 0; r < 4; ++r) {
        const int m = rowbase + mi * 16 + r;
        float v = acc[mi][ni][r] + bv;
        if (!isK) {
          qb[(size_t)m * 512 + col] = f2bf(v * SCALE_Q);
        } else {
          float p = __shfl_xor(v, 1);
          const int d = col - 512;
          const int t = m & 511;
          const float c = cosT[t * 256 + (d >> 1)];
          const float s = sinT[t * 256 + (d >> 1)];
          float o = (d & 1) ? (v * c - p * s) : (v * c + p * s);
          kb[(size_t)m * 512 + d] = f2bf(o);
        }
      }
    }
  }
}

// 32x32 tiled bf16 transpose per batch: krot[b][t][d] -> krotT[b][d][t]
__global__ void transpose_bf(const unsigned short* __restrict__ in,
                             unsigned short* __restrict__ out) {
  __shared__ unsigned short tile[32][33];
  const int b = blockIdx.z;
  const int t0 = blockIdx.x * 32, d0 = blockIdx.y * 32;
  const int x = threadIdx.x, y = threadIdx.y;
  const unsigned short* src = in + (size_t)b * 262144;
  unsigned short* dst = out + (size_t)b * 262144;
#pragma unroll
  for (int r = 0; r < 32; r += 8)
    tile[y + r][x] = src[(size_t)(t0 + y + r) * 512 + d0 + x];
  __syncthreads();
#pragma unroll
  for (int r = 0; r < 32; r += 8)
    dst[(size_t)(d0 + y + r) * 512 + t0 + x] = tile[x][y + r];
}

// ---------------------------------------------------------------------------
// Fused flash attention v9 = v8b + kT prefetch moved to TOP of iteration
// (kT is double-buffered: buf (jt+1)&1 was last read by PV(jt-1), complete
// before A(jt) -> issuing at top is safe and gives a FULL tile of cover).
// krot (single-buffered) still staged post-B. Everything else = R9 (passed).
// ---------------------------------------------------------------------------
#define ATT_LDS 66048

__global__ __launch_bounds__(256, 2) void fused_attn(
    const unsigned short* __restrict__ qb,   // [16][512][512] (scaled)
    const unsigned short* __restrict__ kb,   // [16][512][512] rotated k
    const unsigned short* __restrict__ kTb,  // [16][512][512] d-major
    float* __restrict__ out)                 // [16][512][512]
{
  extern __shared__ char smem[];
  unsigned short* krot_s = (unsigned short*)smem;            // [32][512] 32KB
  unsigned short* kT_s   = (unsigned short*)(smem + 32768);  // 2x[256][32] 32KB
  float*          mls    = (float*)(smem + 65536);           // [rh][jp][16][2]
  float (*buf)[260]      = (float(*)[260])smem;              // merge overlay [32][260]

  const int tid = threadIdx.x;
  const int l   = tid & 63;
  const int w   = tid >> 6;
  const int l15 = l & 15, l4 = l >> 4;
  const int rh = w >> 1, jp = w & 1;

  // Balanced + XCD-pinned decode (v7): b = bid&15; CU c gets strips 15-h / h.
  const int bid = blockIdx.x;
  const int b   = bid & 15;
  const int dh  = (bid >> 4) & 1;
  const int h   = (bid >> 5) & 7;
  const int s   = (bid < 256) ? (15 - h) : h;
  const int nt  = s + 1;                     // j-tiles of 32

  // q B-frags in regs: B[n=i=rh*16+l15][k=ks*32+l4*8]
  s16x8 qf[16];
  {
    const unsigned short* qrow =
        qb + ((size_t)b * 512 + s * 32 + rh * 16 + l15) * 512 + l4 * 8;
#pragma unroll
    for (int ks = 0; ks < 16; ++ks)
      qf[ks] = *(const s16x8*)(qrow + ks * 32);
  }

  f32x4 o[16];            // O[i=rh*16+l4*4+r][d=dh*256+df*16+l15]
#pragma unroll
  for (int i = 0; i < 16; ++i) o[i] = (f32x4){0.f, 0.f, 0.f, 0.f};
  float m_run = -3.0e38f, l_run = 0.f;

  const unsigned short* kbb  = kb  + (size_t)b * 262144;
  const unsigned short* kTbb = kTb + (size_t)b * 262144 + (size_t)dh * 131072;

  // stage krot tile [32 j][512 k], source col pre-swizzled (rule #21)
  auto stage_krot = [&](int jt) {
    const unsigned short* src = kbb + (size_t)jt * 32 * 512;
#pragma unroll
    for (int c = 0; c < 8; ++c) {
      const int jl = w * 8 + c;
      const int colb = (l * 16) ^ ((jl & 7) << 4);
      gload_lds16(src + (size_t)jl * 512 + (colb >> 1), krot_s + jl * 512);
    }
  };
  // stage kT tile [256 d][32 j] into buf jt&1 (16384 B each);
  // 16B chunk slot XOR'd with (d>>1)&3 on the SOURCE side (rule #21).
  auto stage_kT = [&](int jt) {
    unsigned short* dstb = kT_s + (jt & 1) * 8192;   // 8192 shorts = 16384 B
#pragma unroll
    for (int c = 0; c < 4; ++c) {
      const int g = c * 256 + tid;          // linear 16B chunk id, 0..1023
      const int d = g >> 2;
      const int csrc = (g & 3) ^ ((d >> 1) & 3);
      gload_lds16(kTbb + (size_t)d * 512 + jt * 32 + csrc * 8, dstb + g * 8);
    }
  };

  stage_krot(0);
  stage_kT(0);
  __syncthreads();                           // prologue drain

  for (int jt = 0; jt < nt; ++jt) {
    if (jt > 0) __syncthreads();             // A: drains krot(jt)+kT(jt)

    // kT(jt+1) prefetch at TOP: full-tile cover (buffer free since PV(jt-1))
    if (jt + 1 < nt) stage_kT(jt + 1);

    const bool skip = (jt == s) && (rh == 0) && (jp == 1);  // fully-masked

    // ---- QK: S^T frags (A=krot rows of this jp-half, B=q regs) ----
    f32x4 st0 = (f32x4){0.f,0.f,0.f,0.f};
    f32x4 st1 = (f32x4){0.f,0.f,0.f,0.f};
    if (!skip) {
      const int row = jp * 16 + l15;
      const char* kbase = (const char*)krot_s + row * 1024;
      const int swz = (row & 7) << 4;
      __builtin_amdgcn_s_setprio(1);
#pragma unroll
      for (int ks = 0; ks < 16; ks += 2) {
        s16x8 a0 = *(const s16x8*)(kbase + ((ks * 64 + l4 * 16) ^ swz));
        s16x8 a1 = *(const s16x8*)(kbase + (((ks + 1) * 64 + l4 * 16) ^ swz));
        st0 = __builtin_amdgcn_mfma_f32_16x16x32_bf16(a0, qf[ks],     st0, 0,0,0);
        st1 = __builtin_amdgcn_mfma_f32_16x16x32_bf16(a1, qf[ks + 1], st1, 0,0,0);
      }
      __builtin_amdgcn_s_setprio(0);
    }
    BAR_LGKM();                              // B: all QK krot reads done

    // krot(jt+1): restage under softmax+PV (single-buf safe to overwrite)
    if (jt + 1 < nt) stage_krot(jt + 1);

    if (!skip) {
      f32x4 st = st0 + st1;
      if (jt == s) {                         // causal mask (diagonal tile)
#pragma unroll
        for (int r = 0; r < 4; ++r)
          if (jp * 16 + l4 * 4 + r > rh * 16 + l15) st[r] = -3.0e38f;
      }
      // in-register softmax for row i=l15
      float mx = fmaxf(fmaxf(st[0], st[1]), fmaxf(st[2], st[3]));
      mx = fmaxf(mx, __shfl_xor(mx, 16));
      mx = fmaxf(mx, __shfl_xor(mx, 32));
      if (!__all(mx <= m_run + 8.f)) {       // defer-max (T13)
        float mnew = fmaxf(m_run, mx);
        float scl = __expf(m_run - mnew);
        m_run = mnew;
        l_run *= scl;
        MFMA_FENCE();                        // o last written by asm MFMA
        float s0 = __shfl(scl, l4 * 4 + 0);
        float s1 = __shfl(scl, l4 * 4 + 1);
        float s2 = __shfl(scl, l4 * 4 + 2);
        float s3 = __shfl(scl, l4 * 4 + 3);
#pragma unroll
        for (int df = 0; df < 16; ++df) {
          o[df][0] *= s0; o[df][1] *= s1; o[df][2] *= s2; o[df][3] *= s3;
        }
      }
      float p0 = __expf(st[0] - m_run), p1 = __expf(st[1] - m_run);
      float p2 = __expf(st[2] - m_run), p3 = __expf(st[3] - m_run);
      float ps = (p0 + p1) + (p2 + p3);
      ps += __shfl_xor(ps, 16);
      ps += __shfl_xor(ps, 32);
      l_run += ps;
      s16x4 pb;
      pb[0] = (short)f2bf(p0); pb[1] = (short)f2bf(p1);
      pb[2] = (short)f2bf(p2); pb[3] = (short)f2bf(p3);

      // ---- PV: O += P * krot (B-frags from swizzled kT_s, ds_read_b64) ----
      s16x4 av[16];
      {
        const char* ktb = (const char*)kT_s + (jt & 1) * 16384;
        const int cw = jp * 2 + (l4 >> 1);   // wanted 16B chunk of the row
        const int half = (l4 & 1) * 8;
#pragma unroll
        for (int df = 0; df < 16; ++df) {
          const int d = df * 16 + l15;
          av[df] = *(const s16x4*)(ktb + d * 64 +
                                   (((cw ^ ((d >> 1) & 3)) << 4) + half));
        }
      }
      __builtin_amdgcn_sched_barrier(0);
      asm volatile("s_nop 3");               // VALU->MFMA src hazard gap
      __builtin_amdgcn_s_setprio(1);
#pragma unroll
      for (int df = 0; df < 16; ++df)
        o[df] = mfma16x16x16(pb, av[df], o[df]);
      __builtin_amdgcn_s_setprio(0);
    }
  }

  // ---- merge jp partials (v6-verified) ----
  MFMA_FENCE();
  __syncthreads();                           // all LDS reads done; overlay buf
  if (l4 == 0) {
    mls[((rh * 2 + jp) * 16 + l15) * 2 + 0] = m_run;
    mls[((rh * 2 + jp) * 16 + l15) * 2 + 1] = l_run;
  }
  __syncthreads();
  if (jp == 0) {
    float m1 = mls[((rh * 2 + 1) * 16 + l15) * 2 + 0];
    float m  = fmaxf(m_run, m1);
    float e0 = __expf(m_run - m);
    float e0r[4];
#pragma unroll
    for (int r = 0; r < 4; ++r) e0r[r] = __shfl(e0, l4 * 4 + r);
#pragma unroll
    for (int df = 0; df < 16; ++df)
#pragma unroll
      for (int r = 0; r < 4; ++r)
        buf[rh * 16 + l4 * 4 + r][df * 16 + l15] = o[df][r] * e0r[r];
  }
  __syncthreads();
  if (jp == 1) {
    float m0 = mls[((rh * 2 + 0) * 16 + l15) * 2 + 0];
    float l0 = mls[((rh * 2 + 0) * 16 + l15) * 2 + 1];
    float m  = fmaxf(m_run, m0);
    float e1 = __expf(m_run - m), e0 = __expf(m0 - m);
    float inv = 1.0f / (l0 * e0 + l_run * e1);
    float e1r[4], invr[4];
#pragma unroll
    for (int r = 0; r < 4; ++r) {
      e1r[r]  = __shfl(e1,  l4 * 4 + r);
      invr[r] = __shfl(inv, l4 * 4 + r);
    }
#pragma unroll
    for (int df = 0; df < 16; ++df)
#pragma unroll
      for (int r = 0; r < 4; ++r) {
        float* p = &buf[rh * 16 + l4 * 4 + r][df * 16 + l15];
        *p = (*p + o[df][r] * e1r[r]) * invr[r];
      }
  }
  __syncthreads();

  // ---- coalesced output: wave (rh,jp) writes 8 rows of its rh half ----
  float* ob = out + ((size_t)b * 512 + s * 32 + rh * 16) * 512 + dh * 256;
#pragma unroll
  for (int rr = 0; rr < 8; ++rr) {
    const int row = jp * 8 + rr;
    f32x4 v = *(const f32x4*)&buf[rh * 16 + row][l * 4];
    *(f32x4*)(ob + (size_t)row * 512 + l * 4) = v;
  }
}

// ---------------------------------------------------------------------------
extern "C" void kernel_launch(void* const* d_in, const int* in_sizes, int n_in,
                              void* d_out, int out_size, void* d_ws, size_t ws_size,
                              hipStream_t stream) {
  (void)in_sizes; (void)n_in; (void)out_size; (void)ws_size;
  const float* x    = (const float*)d_in[0];   // [16,512,512]
  const float* W    = (const float*)d_in[1];   // [1536,512]
  const float* bias = (const float*)d_in[2];   // [1536]
  float* out = (float*)d_out;                  // [16,512,512]
  char* ws = (char*)d_ws;

  float* cosT            = (float*)(ws);                    // 512*256 f32
  float* sinT            = (float*)(ws + 524288);
  unsigned short* xb     = (unsigned short*)(ws + 1048576); // [8192,512] bf16
  unsigned short* Wb     = (unsigned short*)(ws + 9437184); // [1024,512] bf16
  unsigned short* qb     = (unsigned short*)(ws + 10485760);// [16,512,512] bf16 (scaled)
  unsigned short* kb     = (unsigned short*)(ws + 18874368);// krot
  unsigned short* kTb    = (unsigned short*)(ws + 27262976);// krot^T

  prep<<<2816, 256, 0, stream>>>(x, W, xb, Wb, cosT, sinT);
  gemm_qk<<<dim3(64, 8), 256, 0, stream>>>(xb, Wb, bias, cosT, sinT, qb, kb);
  transpose_bf<<<dim3(16, 16, 16), dim3(32, 8), 0, stream>>>(kb, kTb);
  fused_attn<<<512, 256, ATT_LDS, stream>>>(qb, kb, kTb, out);
}

// Round 12
// 66.696 us; speedup vs baseline: 1.1874x; 1.1874x over previous
//
#include <hip/hip_runtime.h>
#include <hip/hip_bf16.h>

typedef float  f32x4  __attribute__((ext_vector_type(4)));
typedef short  s16x8  __attribute__((ext_vector_type(8)));
typedef short  s16x4  __attribute__((ext_vector_type(4)));
typedef unsigned short u16x8 __attribute__((ext_vector_type(8)));
typedef unsigned short u16x4 __attribute__((ext_vector_type(4)));

#define T_  512
#define D_  512
#define BTD 4194304   // 16*512*512
#define SCALE_Q 0.044194173824159216f   // 1/sqrt(512)

static __device__ __forceinline__ unsigned short f2bf(float f) {
  unsigned u = __builtin_bit_cast(unsigned, f);
  u += 0x7fffu + ((u >> 16) & 1u);
  return (unsigned short)(u >> 16);
}

static __device__ __forceinline__ void gload_lds16(const void* g, void* l) {
  __builtin_amdgcn_global_load_lds(
      (__attribute__((address_space(1))) void*)(g),
      (__attribute__((address_space(3))) void*)(l),
      16, 0, 0);
}

// K=16 bf16 MFMA (v6-proven). asm MFMA: compiler does not insert hazard nops;
// fence (MFMA_FENCE) before any VALU read of the accumulator, s_nop before use.
static __device__ __forceinline__ f32x4 mfma16x16x16(s16x4 a, s16x4 b, f32x4 c) {
  asm("v_mfma_f32_16x16x16_bf16 %0, %1, %2, %0" : "+v"(c) : "v"(a), "v"(b));
  return c;
}
#define MFMA_FENCE()                                   \
  do {                                                 \
    __builtin_amdgcn_sched_barrier(0);                 \
    asm volatile("s_nop 7\n\ts_nop 7");                \
    __builtin_amdgcn_sched_barrier(0);                 \
  } while (0)

// s_barrier without vmcnt drain (prefetches stay in flight); lgkm only.
#define BAR_LGKM()                                          \
  do {                                                      \
    __builtin_amdgcn_sched_barrier(0);                      \
    asm volatile("s_waitcnt lgkmcnt(0)" ::: "memory");      \
    __builtin_amdgcn_sched_barrier(0);                      \
    __builtin_amdgcn_s_barrier();                           \
    __builtin_amdgcn_sched_barrier(0);                      \
  } while (0)

// ---------------------------------------------------------------------------
// 128x128-tile bt-GEMM mainloop (R9-proven, single-buffered):
// C += A[M,K] * B[N,K]^T.
// ---------------------------------------------------------------------------
__device__ __forceinline__ void gemm_mainloop(
    const unsigned short* __restrict__ A,
    const unsigned short* __restrict__ B,
    int lda, int ldb, int ksteps,
    unsigned short* ldsA, unsigned short* ldsB,
    f32x4 acc[4][4])
{
  const int tid  = threadIdx.x;
  const int lane = tid & 63;
  const int wave = tid >> 6;
  const int wr = wave >> 1, wc = wave & 1;

  const int c0 = wave, c1 = wave + 4;
  const int ks0 = c0 >> 1, r00 = (c0 & 1) * 64;
  const int ks1 = c1 >> 1, r01 = (c1 & 1) * 64;

  const char* ldsAc = (const char*)ldsA;
  const char* ldsBc = (const char*)ldsB;
  const int offA = (lane >> 4) * 2048 + (wr * 64 + (lane & 15)) * 16;
  const int offB = (lane >> 4) * 2048 + (wc * 64 + (lane & 15)) * 16;

  for (int kt = 0; kt < ksteps; ++kt) {
    const unsigned short* Ak = A + kt * 32;
    const unsigned short* Bk = B + kt * 32;
    gload_lds16(Ak + (size_t)(r00 + lane) * lda + ks0 * 8, ldsA + c0 * 512);
    gload_lds16(Ak + (size_t)(r01 + lane) * lda + ks1 * 8, ldsA + c1 * 512);
    gload_lds16(Bk + (size_t)(r00 + lane) * ldb + ks0 * 8, ldsB + c0 * 512);
    gload_lds16(Bk + (size_t)(r01 + lane) * ldb + ks1 * 8, ldsB + c1 * 512);
    __syncthreads();
    s16x8 af[4], bfr[4];
#pragma unroll
    for (int mi = 0; mi < 4; ++mi)
      af[mi] = *(const s16x8*)(ldsAc + offA + mi * 256);
#pragma unroll
    for (int ni = 0; ni < 4; ++ni)
      bfr[ni] = *(const s16x8*)(ldsBc + offB + ni * 256);
#pragma unroll
    for (int mi = 0; mi < 4; ++mi)
#pragma unroll
      for (int ni = 0; ni < 4; ++ni)
        acc[mi][ni] = __builtin_amdgcn_mfma_f32_16x16x32_bf16(
            af[mi], bfr[ni], acc[mi][ni], 0, 0, 0);
    __syncthreads();
  }
}

#define ZERO_ACC(acc)                                        \
  _Pragma("unroll") for (int za = 0; za < 4; ++za)           \
  _Pragma("unroll") for (int zb = 0; zb < 4; ++zb)           \
      acc[za][zb] = (f32x4){0.f, 0.f, 0.f, 0.f};

// ---------------------------------------------------------------------------
// prep: rope tables + x->bf16 + W->bf16 (one launch)
// ---------------------------------------------------------------------------
__global__ __launch_bounds__(256) void prep(
    const float* __restrict__ x, const float* __restrict__ W,
    unsigned short* __restrict__ xb, unsigned short* __restrict__ Wb,
    float* __restrict__ cosT, float* __restrict__ sinT)
{
  const int bid = blockIdx.x, tid = threadIdx.x;
  if (bid < 2048) {
    int idx = (bid * 256 + tid) * 8;
    f32x4 a = *(const f32x4*)(x + idx);
    f32x4 b = *(const f32x4*)(x + idx + 4);
    u16x8 o;
    o[0]=f2bf(a[0]); o[1]=f2bf(a[1]); o[2]=f2bf(a[2]); o[3]=f2bf(a[3]);
    o[4]=f2bf(b[0]); o[5]=f2bf(b[1]); o[6]=f2bf(b[2]); o[7]=f2bf(b[3]);
    *(u16x8*)(xb + idx) = o;
  } else if (bid < 2304) {
    int idx = ((bid - 2048) * 256 + tid) * 8;
    f32x4 a = *(const f32x4*)(W + idx);
    f32x4 b = *(const f32x4*)(W + idx + 4);
    u16x8 o;
    o[0]=f2bf(a[0]); o[1]=f2bf(a[1]); o[2]=f2bf(a[2]); o[3]=f2bf(a[3]);
    o[4]=f2bf(b[0]); o[5]=f2bf(b[1]); o[6]=f2bf(b[2]); o[7]=f2bf(b[3]);
    *(u16x8*)(Wb + idx) = o;
  } else {
    int idx = (bid - 2304) * 256 + tid;     // 512*256 entries
    int t = idx >> 8, i = idx & 255;
    float theta = expf(-9.210340371976184f * (float)(2 * i) * (1.0f / 512.0f));
    float s, c;
    sincosf((float)(t + 1) * theta, &s, &c);
    cosT[idx] = c;
    sinT[idx] = s;
  }
}

// ---------------------------------------------------------------------------
// GEMM1: qkv projection (q,k only). q pre-scaled by 1/sqrt(D). k gets RoPE,
// written BOTH row-major (kb) and transposed (kTb) — transpose kernel fused.
// r=0..3 are consecutive in m, so the kTb write packs as one u16x4 (8B).
// ---------------------------------------------------------------------------
__global__ __launch_bounds__(256) void gemm_qk(
    const unsigned short* __restrict__ xb, const unsigned short* __restrict__ Wb,
    const float* __restrict__ bias, const float* __restrict__ cosT,
    const float* __restrict__ sinT, unsigned short* __restrict__ qb,
    unsigned short* __restrict__ kb, unsigned short* __restrict__ kTb) {
  __shared__ __align__(16) unsigned short ldsA[4096];
  __shared__ __align__(16) unsigned short ldsB[4096];
  const int bm = blockIdx.x, bn = blockIdx.y;
  f32x4 acc[4][4];
  ZERO_ACC(acc);
  gemm_mainloop(xb + (size_t)bm * 128 * 512, Wb + (size_t)bn * 128 * 512,
                512, 512, 16, ldsA, ldsB, acc);
  const int lane = threadIdx.x & 63, wave = threadIdx.x >> 6;
  const int wr = wave >> 1, wc = wave & 1;
  const int rowbase = bm * 128 + wr * 64 + ((lane >> 4) << 2);
  const int colbase = bn * 128 + wc * 64 + (lane & 15);
  const bool isK = (bn >= 4);
  // batch-row decomposition: m = b*512 + t  (t = m & 511)
#pragma unroll
  for (int ni = 0; ni < 4; ++ni) {
    const int col = colbase + ni * 16;
    const float bv = bias[col];
#pragma unroll
    for (int mi = 0; mi < 4; ++mi) {
      if (!isK) {
#pragma unroll
        for (int r = 0; r < 4; ++r) {
          const int m = rowbase + mi * 16 + r;
          float v = acc[mi][ni][r] + bv;
          qb[(size_t)m * 512 + col] = f2bf(v * SCALE_Q);
        }
      } else {
        const int d = col - 512;
        u16x4 kv;
#pragma unroll
        for (int r = 0; r < 4; ++r) {
          const int m = rowbase + mi * 16 + r;
          float v = acc[mi][ni][r] + bv;
          float p = __shfl_xor(v, 1);
          const int t = m & 511;
          const float c = cosT[t * 256 + (d >> 1)];
          const float s = sinT[t * 256 + (d >> 1)];
          float o = (d & 1) ? (v * c - p * s) : (v * c + p * s);
          unsigned short ob = f2bf(o);
          kb[(size_t)m * 512 + d] = ob;
          kv[r] = ob;
        }
        // transposed write: kTb[b][d][t] — m-range rowbase+mi*16..+3 is one
        // batch-contiguous run (128-row block never crosses a 512 boundary).
        *(u16x4*)(kTb + (size_t)d * 512 +
                  (size_t)(rowbase >> 9) * 262144 +    // batch offset
                  ((rowbase & 511) + mi * 16)) = kv;
      }
    }
  }
}

// ---------------------------------------------------------------------------
// Fused flash attention v8b (R9-verified, 77.0us config, byte-identical).
// Block (b, 32-row strip, dh). Waves = (rh row-half, jp j-parity).
// Per 32-j tile: S^T = mfma(A=krot_frag, B=q_frag) -> lane holds
// S^T[j=jp*16+l4*4+r][i=l15]; softmax per-lane + shfl_xor(16,32); exp'd
// frag IS the A-frag of the K=16 PV MFMA. 2 barriers/tile.
// ---------------------------------------------------------------------------
#define ATT_LDS 66048

__global__ __launch_bounds__(256, 2) void fused_attn(
    const unsigned short* __restrict__ qb,   // [16][512][512] (scaled)
    const unsigned short* __restrict__ kb,   // [16][512][512] rotated k
    const unsigned short* __restrict__ kTb,  // [16][512][512] d-major
    float* __restrict__ out)                 // [16][512][512]
{
  extern __shared__ char smem[];
  unsigned short* krot_s = (unsigned short*)smem;            // [32][512] 32KB
  unsigned short* kT_s   = (unsigned short*)(smem + 32768);  // 2x[256][32] 32KB
  float*          mls    = (float*)(smem + 65536);           // [rh][jp][16][2]
  float (*buf)[260]      = (float(*)[260])smem;              // merge overlay [32][260]

  const int tid = threadIdx.x;
  const int l   = tid & 63;
  const int w   = tid >> 6;
  const int l15 = l & 15, l4 = l >> 4;
  const int rh = w >> 1, jp = w & 1;

  // Balanced + XCD-pinned decode (v7): b = bid&15; CU c gets strips 15-h / h.
  const int bid = blockIdx.x;
  const int b   = bid & 15;
  const int dh  = (bid >> 4) & 1;
  const int h   = (bid >> 5) & 7;
  const int s   = (bid < 256) ? (15 - h) : h;
  const int nt  = s + 1;                     // j-tiles of 32

  // q B-frags in regs: B[n=i=rh*16+l15][k=ks*32+l4*8]
  s16x8 qf[16];
  {
    const unsigned short* qrow =
        qb + ((size_t)b * 512 + s * 32 + rh * 16 + l15) * 512 + l4 * 8;
#pragma unroll
    for (int ks = 0; ks < 16; ++ks)
      qf[ks] = *(const s16x8*)(qrow + ks * 32);
  }

  f32x4 o[16];            // O[i=rh*16+l4*4+r][d=dh*256+df*16+l15]
#pragma unroll
  for (int i = 0; i < 16; ++i) o[i] = (f32x4){0.f, 0.f, 0.f, 0.f};
  float m_run = -3.0e38f, l_run = 0.f;

  const unsigned short* kbb  = kb  + (size_t)b * 262144;
  const unsigned short* kTbb = kTb + (size_t)b * 262144 + (size_t)dh * 131072;

  // stage krot tile [32 j][512 k], source col pre-swizzled (rule #21)
  auto stage_krot = [&](int jt) {
    const unsigned short* src = kbb + (size_t)jt * 32 * 512;
#pragma unroll
    for (int c = 0; c < 8; ++c) {
      const int jl = w * 8 + c;
      const int colb = (l * 16) ^ ((jl & 7) << 4);
      gload_lds16(src + (size_t)jl * 512 + (colb >> 1), krot_s + jl * 512);
    }
  };
  // stage kT tile [256 d][32 j] into buf jt&1 (16384 B each);
  // 16B chunk slot XOR'd with (d>>1)&3 on the SOURCE side (rule #21).
  auto stage_kT = [&](int jt) {
    unsigned short* dstb = kT_s + (jt & 1) * 8192;   // 8192 shorts = 16384 B
#pragma unroll
    for (int c = 0; c < 4; ++c) {
      const int g = c * 256 + tid;          // linear 16B chunk id, 0..1023
      const int d = g >> 2;
      const int csrc = (g & 3) ^ ((d >> 1) & 3);
      gload_lds16(kTbb + (size_t)d * 512 + jt * 32 + csrc * 8, dstb + g * 8);
    }
  };

  stage_krot(0);
  stage_kT(0);
  __syncthreads();                           // prologue drain

  for (int jt = 0; jt < nt; ++jt) {
    if (jt > 0) __syncthreads();             // A: drains stage(jt)

    const bool skip = (jt == s) && (rh == 0) && (jp == 1);  // fully-masked

    // ---- QK: S^T frags (A=krot rows of this jp-half, B=q regs) ----
    f32x4 st0 = (f32x4){0.f,0.f,0.f,0.f};
    f32x4 st1 = (f32x4){0.f,0.f,0.f,0.f};
    if (!skip) {
      const int row = jp * 16 + l15;
      const char* kbase = (const char*)krot_s + row * 1024;
      const int swz = (row & 7) << 4;
      __builtin_amdgcn_s_setprio(1);
#pragma unroll
      for (int ks = 0; ks < 16; ks += 2) {
        s16x8 a0 = *(const s16x8*)(kbase + ((ks * 64 + l4 * 16) ^ swz));
        s16x8 a1 = *(const s16x8*)(kbase + (((ks + 1) * 64 + l4 * 16) ^ swz));
        st0 = __builtin_amdgcn_mfma_f32_16x16x32_bf16(a0, qf[ks],     st0, 0,0,0);
        st1 = __builtin_amdgcn_mfma_f32_16x16x32_bf16(a1, qf[ks + 1], st1, 0,0,0);
      }
      __builtin_amdgcn_s_setprio(0);
    }
    BAR_LGKM();                              // B: all QK krot reads done

    // restage under softmax+PV (krot single-buf now safe to overwrite)
    if (jt + 1 < nt) { stage_krot(jt + 1); stage_kT(jt + 1); }

    if (!skip) {
      f32x4 st = st0 + st1;
      if (jt == s) {                         // causal mask (diagonal tile)
#pragma unroll
        for (int r = 0; r < 4; ++r)
          if (jp * 16 + l4 * 4 + r > rh * 16 + l15) st[r] = -3.0e38f;
      }
      // in-register softmax for row i=l15
      float mx = fmaxf(fmaxf(st[0], st[1]), fmaxf(st[2], st[3]));
      mx = fmaxf(mx, __shfl_xor(mx, 16));
      mx = fmaxf(mx, __shfl_xor(mx, 32));
      if (!__all(mx <= m_run + 8.f)) {       // defer-max (T13)
        float mnew = fmaxf(m_run, mx);
        float scl = __expf(m_run - mnew);
        m_run = mnew;
        l_run *= scl;
        MFMA_FENCE();                        // o last written by asm MFMA
        float s0 = __shfl(scl, l4 * 4 + 0);
        float s1 = __shfl(scl, l4 * 4 + 1);
        float s2 = __shfl(scl, l4 * 4 + 2);
        float s3 = __shfl(scl, l4 * 4 + 3);
#pragma unroll
        for (int df = 0; df < 16; ++df) {
          o[df][0] *= s0; o[df][1] *= s1; o[df][2] *= s2; o[df][3] *= s3;
        }
      }
      float p0 = __expf(st[0] - m_run), p1 = __expf(st[1] - m_run);
      float p2 = __expf(st[2] - m_run), p3 = __expf(st[3] - m_run);
      float ps = (p0 + p1) + (p2 + p3);
      ps += __shfl_xor(ps, 16);
      ps += __shfl_xor(ps, 32);
      l_run += ps;
      s16x4 pb;
      pb[0] = (short)f2bf(p0); pb[1] = (short)f2bf(p1);
      pb[2] = (short)f2bf(p2); pb[3] = (short)f2bf(p3);

      // ---- PV: O += P * krot (B-frags from swizzled kT_s, ds_read_b64) ----
      s16x4 av[16];
      {
        const char* ktb = (const char*)kT_s + (jt & 1) * 16384;
        const int cw = jp * 2 + (l4 >> 1);   // wanted 16B chunk of the row
        const int half = (l4 & 1) * 8;
#pragma unroll
        for (int df = 0; df < 16; ++df) {
          const int d = df * 16 + l15;
          av[df] = *(const s16x4*)(ktb + d * 64 +
                                   (((cw ^ ((d >> 1) & 3)) << 4) + half));
        }
      }
      __builtin_amdgcn_sched_barrier(0);
      asm volatile("s_nop 3");               // VALU->MFMA src hazard gap
      __builtin_amdgcn_s_setprio(1);
#pragma unroll
      for (int df = 0; df < 16; ++df)
        o[df] = mfma16x16x16(pb, av[df], o[df]);
      __builtin_amdgcn_s_setprio(0);
    }
  }

  // ---- merge jp partials (v6-verified) ----
  MFMA_FENCE();
  __syncthreads();                           // all LDS reads done; overlay buf
  if (l4 == 0) {
    mls[((rh * 2 + jp) * 16 + l15) * 2 + 0] = m_run;
    mls[((rh * 2 + jp) * 16 + l15) * 2 + 1] = l_run;
  }
  __syncthreads();
  if (jp == 0) {
    float m1 = mls[((rh * 2 + 1) * 16 + l15) * 2 + 0];
    float m  = fmaxf(m_run, m1);
    float e0 = __expf(m_run - m);
    float e0r[4];
#pragma unroll
    for (int r = 0; r < 4; ++r) e0r[r] = __shfl(e0, l4 * 4 + r);
#pragma unroll
    for (int df = 0; df < 16; ++df)
#pragma unroll
      for (int r = 0; r < 4; ++r)
        buf[rh * 16 + l4 * 4 + r][df * 16 + l15] = o[df][r] * e0r[r];
  }
  __syncthreads();
  if (jp == 1) {
    float m0 = mls[((rh * 2 + 0) * 16 + l15) * 2 + 0];
    float l0 = mls[((rh * 2 + 0) * 16 + l15) * 2 + 1];
    float m  = fmaxf(m_run, m0);
    float e1 = __expf(m_run - m), e0 = __expf(m0 - m);
    float inv = 1.0f / (l0 * e0 + l_run * e1);
    float e1r[4], invr[4];
#pragma unroll
    for (int r = 0; r < 4; ++r) {
      e1r[r]  = __shfl(e1,  l4 * 4 + r);
      invr[r] = __shfl(inv, l4 * 4 + r);
    }
#pragma unroll
    for (int df = 0; df < 16; ++df)
#pragma unroll
      for (int r = 0; r < 4; ++r) {
        float* p = &buf[rh * 16 + l4 * 4 + r][df * 16 + l15];
        *p = (*p + o[df][r] * e1r[r]) * invr[r];
      }
  }
  __syncthreads();

  // ---- coalesced output: wave (rh,jp) writes 8 rows of its rh half ----
  float* ob = out + ((size_t)b * 512 + s * 32 + rh * 16) * 512 + dh * 256;
#pragma unroll
  for (int rr = 0; rr < 8; ++rr) {
    const int row = jp * 8 + rr;
    f32x4 v = *(const f32x4*)&buf[rh * 16 + row][l * 4];
    *(f32x4*)(ob + (size_t)row * 512 + l * 4) = v;
  }
}

// ---------------------------------------------------------------------------
extern "C" void kernel_launch(void* const* d_in, const int* in_sizes, int n_in,
                              void* d_out, int out_size, void* d_ws, size_t ws_size,
                              hipStream_t stream) {
  (void)in_sizes; (void)n_in; (void)out_size; (void)ws_size;
  const float* x    = (const float*)d_in[0];   // [16,512,512]
  const float* W    = (const float*)d_in[1];   // [1536,512]
  const float* bias = (const float*)d_in[2];   // [1536]
  float* out = (float*)d_out;                  // [16,512,512]
  char* ws = (char*)d_ws;

  float* cosT            = (float*)(ws);                    // 512*256 f32
  float* sinT            = (float*)(ws + 524288);
  unsigned short* xb     = (unsigned short*)(ws + 1048576); // [8192,512] bf16
  unsigned short* Wb     = (unsigned short*)(ws + 9437184); // [1024,512] bf16
  unsigned short* qb     = (unsigned short*)(ws + 10485760);// [16,512,512] bf16 (scaled)
  unsigned short* kb     = (unsigned short*)(ws + 18874368);// krot
  unsigned short* kTb    = (unsigned short*)(ws + 27262976);// krot^T

  prep<<<2816, 256, 0, stream>>>(x, W, xb, Wb, cosT, sinT);
  gemm_qk<<<dim3(64, 8), 256, 0, stream>>>(xb, Wb, bias, cosT, sinT, qb, kb, kTb);
  fused_attn<<<512, 256, ATT_LDS, stream>>>(qb, kb, kTb, out);
}